// Round 12
// baseline (541.429 us; speedup 1.0000x reference)
//
#include <hip/hip_runtime.h>
#include <cstdint>
#include <cstddef>

typedef unsigned short u16;
typedef float f32x4 __attribute__((ext_vector_type(4)));
typedef short short8 __attribute__((ext_vector_type(8)));
typedef int i32x4 __attribute__((ext_vector_type(4)));

// ---------------- helpers ----------------

__device__ __forceinline__ float geluf(float v) {  // exact (libm erff)
  return 0.5f * v * (1.0f + erff(v * 0.70710678118654752440f));
}

// Abramowitz-Stegun 7.1.26: |err| <= 1.5e-7 abs.
__device__ __forceinline__ float erf_fast(float x) {
  const float ax = fabsf(x);
  const float t = __builtin_amdgcn_rcpf(fmaf(0.3275911f, ax, 1.0f));
  float p = fmaf(1.061405429f, t, -1.453152027f);
  p = fmaf(p, t, 1.421413741f);
  p = fmaf(p, t, -0.284496736f);
  p = fmaf(p, t, 0.254829592f);
  p = p * t;
  const float e = __expf(-ax * ax);
  const float r = fmaf(-p, e, 1.0f);
  return copysignf(r, x);
}
__device__ __forceinline__ float gelu_fast(float v) {
  return 0.5f * v * (1.0f + erf_fast(v * 0.70710678118654752440f));
}

__device__ __forceinline__ u16 f2bf(float f) {  // RNE fp32 -> bf16 bits
  unsigned u = __float_as_uint(f);
  u = (u + 0x7FFFu + ((u >> 16) & 1u)) >> 16;
  return (u16)u;
}
__device__ __forceinline__ float bf2f(u16 h) {
  return __uint_as_float(((unsigned)h) << 16);
}

__device__ __forceinline__ void waveRed2(float& s, float& s2) {
#pragma unroll
  for (int m = 1; m < 64; m <<= 1) {
    s += __shfl_xor(s, m);
    s2 += __shfl_xor(s2, m);
  }
}

// ---------------- LN over 512 (fp32 out — score-critical) ----------------
__global__ __launch_bounds__(256) void k_ln512(const float* __restrict__ x,
                                               const float* __restrict__ g,
                                               const float* __restrict__ b,
                                               float* __restrict__ out) {
  __shared__ float red[8];
  const int t = blockIdx.x, tid = threadIdx.x;
  const float v0 = x[(size_t)t * 512 + tid];
  const float v1 = x[(size_t)t * 512 + 256 + tid];
  float s = v0 + v1, s2 = v0 * v0 + v1 * v1;
  waveRed2(s, s2);
  if ((tid & 63) == 0) { red[(tid >> 6) * 2] = s; red[(tid >> 6) * 2 + 1] = s2; }
  __syncthreads();
  s = red[0] + red[2] + red[4] + red[6];
  s2 = red[1] + red[3] + red[5] + red[7];
  const float mu = s * (1.f / 512.f);
  const float var = fmaxf(s2 * (1.f / 512.f) - mu * mu, 0.f);
  const float rstd = 1.f / sqrtf(var + 1e-5f);
  out[(size_t)t * 512 + tid] = (v0 - mu) * rstd * g[tid] + b[tid];
  out[(size_t)t * 512 + 256 + tid] = (v1 - mu) * rstd * g[tid + 256] + b[tid + 256];
}

// ---------------- fused prep: nvphi + pW2T + rW1T + rW2T + Wr2b ----------------
__global__ __launch_bounds__(256) void k_prep(
    const float* __restrict__ nv, const float* __restrict__ pW1,
    const float* __restrict__ pb1, float* __restrict__ nvphi,
    const float* __restrict__ pW2, u16* __restrict__ pW2T,
    const float* __restrict__ rW1, u16* __restrict__ rW1T,
    const float* __restrict__ rW2, u16* __restrict__ rW2T,
    const float* __restrict__ Wr2, u16* __restrict__ Wr2b) {
  __shared__ float nvs[128];
  const int b = blockIdx.x, tid = threadIdx.x;
  if (b < 2048) {
    const int n = b;
    if (tid < 128) nvs[tid] = nv[n * 128 + tid];
    __syncthreads();
    float s = pb1[tid];
#pragma unroll 4
    for (int i = 0; i < 128; ++i) s = fmaf(nvs[i], pW1[i * 256 + tid], s);
    nvphi[n * 256 + tid] = s;
  } else if (b < 2304) {
    const int n = b - 2048;
    pW2T[n * 256 + tid] = f2bf(pW2[tid * 256 + n]);
  } else if (b < 2816) {
    const int n = b - 2304;
    if (tid < 256) rW1T[(size_t)n * 256 + tid] = f2bf(rW1[(size_t)tid * 512 + n]);
  } else if (b < 3328) {
    const int n = b - 2816;
    for (int k = tid; k < 512; k += 256)
      rW2T[(size_t)n * 512 + k] = f2bf(rW2[(size_t)k * 512 + n]);
  } else {
    const int i = (b - 3328) * 256 + tid;
    Wr2b[i] = f2bf(Wr2[i]);
  }
}

// ---------------- 128x128 fp32 GEMM, C = act(A[M,K] @ B[N,K]^T) ----------------
template <int GMODE, bool BF16OUT>
__global__ __launch_bounds__(256) void gemm8f(const float* __restrict__ A,
                                              const float* __restrict__ B,
                                              float* __restrict__ C,
                                              u16* __restrict__ Cb, int M,
                                              int N, int K) {
  __shared__ float As[16][132];
  __shared__ float Bs[16][132];
  const int tid = threadIdx.x;
  const int tm = tid >> 4, tn = tid & 15;
  const int m0 = blockIdx.y * 128, n0 = blockIdx.x * 128;
  const int sr = tid >> 1, sk = (tid & 1) * 8;
  const float* gA = &A[(size_t)(m0 + sr) * K + sk];
  const float* gB = &B[(size_t)(n0 + sr) * K + sk];
  float acc[8][8] = {};
  for (int k0 = 0; k0 < K; k0 += 16) {
    const float4 a0 = *(const float4*)&gA[k0];
    const float4 a1 = *(const float4*)&gA[k0 + 4];
    const float4 b0 = *(const float4*)&gB[k0];
    const float4 b1 = *(const float4*)&gB[k0 + 4];
    __syncthreads();
    As[sk + 0][sr] = a0.x; As[sk + 1][sr] = a0.y; As[sk + 2][sr] = a0.z; As[sk + 3][sr] = a0.w;
    As[sk + 4][sr] = a1.x; As[sk + 5][sr] = a1.y; As[sk + 6][sr] = a1.z; As[sk + 7][sr] = a1.w;
    Bs[sk + 0][sr] = b0.x; Bs[sk + 1][sr] = b0.y; Bs[sk + 2][sr] = b0.z; Bs[sk + 3][sr] = b0.w;
    Bs[sk + 4][sr] = b1.x; Bs[sk + 5][sr] = b1.y; Bs[sk + 6][sr] = b1.z; Bs[sk + 7][sr] = b1.w;
    __syncthreads();
#pragma unroll
    for (int k = 0; k < 16; ++k) {
      float a[8], b[8];
      *(float4*)&a[0] = *(const float4*)&As[k][tm * 8];
      *(float4*)&a[4] = *(const float4*)&As[k][tm * 8 + 4];
      *(float4*)&b[0] = *(const float4*)&Bs[k][tn * 8];
      *(float4*)&b[4] = *(const float4*)&Bs[k][tn * 8 + 4];
#pragma unroll
      for (int i = 0; i < 8; ++i)
#pragma unroll
        for (int j = 0; j < 8; ++j) acc[i][j] = fmaf(a[i], b[j], acc[i][j]);
    }
  }
#pragma unroll
  for (int i = 0; i < 8; ++i) {
    float4 o0, o1;
    float* p0 = (float*)&o0;
    float* p1 = (float*)&o1;
#pragma unroll
    for (int j = 0; j < 4; ++j) {
      float xv = acc[i][j], yv = acc[i][j + 4];
      if (GMODE == 1) { xv = gelu_fast(xv); yv = gelu_fast(yv); }
      if (GMODE == 2) { xv = geluf(xv); yv = geluf(yv); }
      p0[j] = xv; p1[j] = yv;
    }
    const size_t off = (size_t)(m0 + tm * 8 + i) * N + n0 + tn * 8;
    *(float4*)&C[off] = o0;
    *(float4*)&C[off + 4] = o1;
    if (BF16OUT) {
      ushort4 u0, u1;
      u0.x = f2bf(p0[0]); u0.y = f2bf(p0[1]); u0.z = f2bf(p0[2]); u0.w = f2bf(p0[3]);
      u1.x = f2bf(p1[0]); u1.y = f2bf(p1[1]); u1.z = f2bf(p1[2]); u1.w = f2bf(p1[3]);
      *(ushort4*)&Cb[off] = u0;
      *(ushort4*)&Cb[off + 4] = u1;
    }
  }
}

// ---------------- MFMA GEMM: C = act(A[M,K] @ B[N,K]^T + bias) ----------------
template <int GMODE, bool BIAS, int OUT>
__global__ __launch_bounds__(256) void gemm_mf(const u16* __restrict__ Ahi,
                                               const u16* __restrict__ Bhi,
                                               const float* __restrict__ bias,
                                               void* __restrict__ Cp, int M,
                                               int N, int K) {
  constexpr int ASZ = 64 * 40;
  constexpr int BSZ = 128 * 40;
  __shared__ __align__(16) u16 smem[ASZ + BSZ];
  u16* sAh = smem;
  u16* sBh = smem + ASZ;

  const int tid = threadIdx.x;
  const int w = tid >> 6, lane = tid & 63;
  const int q = lane >> 4, c = lane & 15;
  const int m0 = blockIdx.y * 64, n0 = blockIdx.x * 128;
  const int ra = tid >> 2, ka = (tid & 3) * 8;
  const int rb = tid >> 1, kb = (tid & 1) * 16;
  const u16* gAh = Ahi + (size_t)(m0 + ra) * K + ka;
  const u16* gBh = Bhi + (size_t)(n0 + rb) * K + kb;

  f32x4 acc[8];
#pragma unroll
  for (int ct = 0; ct < 8; ++ct) {
    const float bv = BIAS ? bias[n0 + ct * 16 + c] : 0.f;
    acc[ct] = (f32x4){bv, bv, bv, bv};
  }

  for (int k0 = 0; k0 < K; k0 += 32) {
    const i32x4 vah = *(const i32x4*)(gAh + k0);
    const i32x4 vbh0 = *(const i32x4*)(gBh + k0);
    const i32x4 vbh1 = *(const i32x4*)(gBh + k0 + 8);
    __syncthreads();
    *(i32x4*)&sAh[ra * 40 + ka] = vah;
    *(i32x4*)&sBh[rb * 40 + kb] = vbh0;
    *(i32x4*)&sBh[rb * 40 + kb + 8] = vbh1;
    __syncthreads();
    const int abase = (w * 16 + c) * 40 + q * 8;
    const short8 ah = *(const short8*)&sAh[abase];
#pragma unroll
    for (int ct = 0; ct < 8; ++ct) {
      const int bbase = (ct * 16 + c) * 40 + q * 8;
      const short8 bh = *(const short8*)&sBh[bbase];
      acc[ct] = __builtin_amdgcn_mfma_f32_16x16x32_bf16(ah, bh, acc[ct], 0, 0, 0);
    }
  }
#pragma unroll
  for (int ct = 0; ct < 8; ++ct) {
#pragma unroll
    for (int reg = 0; reg < 4; ++reg) {
      float v = acc[ct][reg];
      if (GMODE == 1) v = gelu_fast(v);
      const size_t off = (size_t)(m0 + w * 16 + q * 4 + reg) * N + n0 + ct * 16 + c;
      if (OUT == 0) ((float*)Cp)[off] = v;
      else          ((u16*)Cp)[off] = f2bf(v);
    }
  }
}

// ---------------- fused: top-64 (approx+exact rescore) THEN act ----------------
// Rescore and act use sub-wave layout: 16 lanes per dot, 4 concurrent dots per
// wave, each lane reading 128B contiguous (8 float4 in flight, coalesced 2KB
// rows) -> ~8x memory-level parallelism vs R11's 1-dot-per-wave chains.
// The dotted vector (h, then x) is hoisted into 32 registers/lane once.
__global__ __launch_bounds__(256) void k_topk_act(
    const u16* __restrict__ scoresb, const float* __restrict__ h,
    const float* __restrict__ Wr2, const float* __restrict__ x,
    const float* __restrict__ W_in, int* __restrict__ idxout,
    float* __restrict__ act) {
  __shared__ float hs[512];
  __shared__ int redc[4];
  __shared__ int cand[160];
  __shared__ float cex[160];
  __shared__ int selidx[64];
  __shared__ unsigned ccnt, cg_cnt, ec;
  __shared__ int eqbuf[64];
  const int t = blockIdx.x, tid = threadIdx.x;
  hs[tid] = h[(size_t)t * 512 + tid];
  hs[tid + 256] = h[(size_t)t * 512 + 256 + tid];
  unsigned key[8];
#pragma unroll
  for (int j = 0; j < 8; ++j) {
    const unsigned u = (unsigned)scoresb[(size_t)t * 2048 + tid + 256 * j];
    key[j] = (u & 0x8000u) ? (0xFFFFu & ~u) : (u | 0x8000u);
  }
  if (tid == 0) ccnt = 0u;
  unsigned lo = 0u, hi = 0xFFFFu;
  while (lo < hi) {
    const unsigned mid = (lo + hi + 1u) >> 1;
    int c = 0;
#pragma unroll
    for (int j = 0; j < 8; ++j) c += (key[j] >= mid);
#pragma unroll
    for (int m = 1; m < 64; m <<= 1) c += __shfl_xor(c, m);
    if ((tid & 63) == 0) redc[tid >> 6] = c;
    __syncthreads();
    const int total = redc[0] + redc[1] + redc[2] + redc[3];
    __syncthreads();
    if (total >= 96) lo = mid; else hi = mid - 1;
  }
#pragma unroll
  for (int j = 0; j < 8; ++j) {
    if (key[j] >= lo) {
      const unsigned pos = atomicAdd(&ccnt, 1u);
      if (pos < 160u) cand[pos] = tid + 256 * j;
    }
  }
  __syncthreads();
  const int cnt = (int)(ccnt < 160u ? ccnt : 160u);
  const int wv = tid >> 6, l = tid & 63;
  const int sub = l >> 4, li = l & 15;
  // hoist h segment [li*32, li*32+32) into registers (one-time LDS reads)
  float hr[32];
#pragma unroll
  for (int j = 0; j < 8; ++j)
    *(float4*)&hr[j * 4] = *(const float4*)&hs[li * 32 + j * 4];
  // exact fp32 rescore: 4 candidates per wave concurrently
  for (int ci = wv * 4 + sub; ci < cnt; ci += 16) {
    const float* Wr = Wr2 + (size_t)cand[ci] * 512 + li * 32;
    float s = 0.f;
#pragma unroll
    for (int j = 0; j < 8; ++j) {
      const float4 w4 = *(const float4*)(Wr + j * 4);
      s = fmaf(w4.x, hr[j * 4 + 0], s);
      s = fmaf(w4.y, hr[j * 4 + 1], s);
      s = fmaf(w4.z, hr[j * 4 + 2], s);
      s = fmaf(w4.w, hr[j * 4 + 3], s);
    }
#pragma unroll
    for (int m = 1; m < 16; m <<= 1) s += __shfl_xor(s, m);
    if (li == 0) cex[ci] = s;
  }
  __syncthreads();
  // exact top-64 among cnt candidates
  unsigned k2 = 0u;
  int myidx = -1;
  const bool valid = tid < cnt;
  if (valid) {
    const unsigned u = __float_as_uint(cex[tid]);
    k2 = (u & 0x80000000u) ? ~u : (u | 0x80000000u);
    myidx = cand[tid];
  }
  if (tid == 0) { cg_cnt = 0u; ec = 0u; }
  unsigned lo2 = 0u, hi2 = 0xFFFFFFFFu;
  while (lo2 < hi2) {
    const unsigned mid = (unsigned)(((unsigned long long)lo2 + hi2 + 1ull) >> 1);
    int c = (valid && k2 >= mid) ? 1 : 0;
#pragma unroll
    for (int m = 1; m < 64; m <<= 1) c += __shfl_xor(c, m);
    if ((tid & 63) == 0) redc[tid >> 6] = c;
    __syncthreads();
    const int total = redc[0] + redc[1] + redc[2] + redc[3];
    __syncthreads();
    if (total >= 64) lo2 = mid; else hi2 = mid - 1;
  }
  if (valid && k2 > lo2) {
    const unsigned pos = atomicAdd(&cg_cnt, 1u);
    idxout[(size_t)t * 64 + pos] = myidx;
    selidx[pos] = myidx;
  } else if (valid && k2 == lo2) {
    const unsigned e = atomicAdd(&ec, 1u);
    if (e < 64u) eqbuf[e] = myidx;
  }
  __syncthreads();
  if (tid == 0) {
    const int cg = (int)cg_cnt;
    int ne = (int)ec; if (ne > 64) ne = 64;
    const int need = 64 - cg;
    for (int i = 1; i < ne; ++i) {
      const int v = eqbuf[i];
      int j = i - 1;
      while (j >= 0 && eqbuf[j] > v) { eqbuf[j + 1] = eqbuf[j]; --j; }
      eqbuf[j + 1] = v;
    }
    for (int i = 0; i < need; ++i) {
      idxout[(size_t)t * 64 + cg + i] = eqbuf[i];
      selidx[cg + i] = eqbuf[i];
    }
  }
  __syncthreads();
  // ---- Part 2: act (reuse hs for x), 4 neurons per wave concurrently ----
  hs[tid] = x[(size_t)t * 512 + tid];
  hs[tid + 256] = x[(size_t)t * 512 + 256 + tid];
  __syncthreads();
  float xr[32];
#pragma unroll
  for (int j = 0; j < 8; ++j)
    *(float4*)&xr[j * 4] = *(const float4*)&hs[li * 32 + j * 4];
#pragma unroll 1
  for (int pass = 0; pass < 4; ++pass) {
    const int k = pass * 16 + wv * 4 + sub;
    const int n = selidx[k];
    const float* Wr = W_in + (size_t)n * 512 + li * 32;
    float s = 0.f;
#pragma unroll
    for (int j = 0; j < 8; ++j) {
      const float4 w4 = *(const float4*)(Wr + j * 4);
      s = fmaf(w4.x, xr[j * 4 + 0], s);
      s = fmaf(w4.y, xr[j * 4 + 1], s);
      s = fmaf(w4.z, xr[j * 4 + 2], s);
      s = fmaf(w4.w, xr[j * 4 + 3], s);
    }
#pragma unroll
    for (int m = 1; m < 16; m <<= 1) s += __shfl_xor(s, m);
    if (li == 0) act[(size_t)t * 64 + k] = gelu_fast(s);
  }
}

// ---------------- fused phi + rho-LN (one token per block) ----------------
// R9-proven core. Phase A now issues ALL 16 nvphi gather loads upfront into
// registers (compile-time indices) to hide gather latency; LDS still pins
// occupancy at 2 blocks/CU so the extra ~64 VGPR are free (R10 lesson:
// VGPR+AGPR share the 256/wave-at-2-blocks budget — watch WRITE_SIZE).
__global__ __launch_bounds__(256, 1) void k_phi(
    const float* __restrict__ nvphi, const float* __restrict__ pW1,
    const float* __restrict__ pln1_g, const float* __restrict__ pln1_b,
    const u16* __restrict__ pW2T, const float* __restrict__ pb2,
    const float* __restrict__ pln2_g, const float* __restrict__ pln2_b,
    const int* __restrict__ idx, const float* __restrict__ act,
    const float* __restrict__ rln_g, const float* __restrict__ rln_b,
    u16* __restrict__ rh) {
  __shared__ __align__(16) u16 h1s[64 * 264];
  __shared__ __align__(16) u16 Bs[64 * 264];
  __shared__ float aggbuf[4 * 256];
  __shared__ float red[8];
  __shared__ int idxs[64];
  __shared__ float acts[64];
  const int tid = threadIdx.x;
  const int t = blockIdx.x;
  const int w = tid >> 6, lane = tid & 63;
  const int q = lane >> 4, c = lane & 15;
  if (tid < 64) {
    idxs[tid] = idx[(size_t)t * 64 + tid];
    acts[tid] = act[(size_t)t * 64 + tid];
  }
  __syncthreads();
  // ---- Phase A: all gather loads upfront, then compute ----
  {
    f32x4 nvv[16];
#pragma unroll
    for (int rd = 0; rd < 4; ++rd) {
      const int n = idxs[w * 16 + rd * 4 + q];
#pragma unroll
      for (int j = 0; j < 4; ++j)
        nvv[rd * 4 + j] = *(const f32x4*)&nvphi[(size_t)n * 256 + c * 16 + j * 4];
    }
    f32x4 w4[4], g1[4], b1[4];
#pragma unroll
    for (int j = 0; j < 4; ++j) {
      w4[j] = *(const f32x4*)&pW1[128 * 256 + c * 16 + j * 4];
      g1[j] = *(const f32x4*)&pln1_g[c * 16 + j * 4];
      b1[j] = *(const f32x4*)&pln1_b[c * 16 + j * 4];
    }
#pragma unroll
    for (int rd = 0; rd < 4; ++rd) {
      const int p = w * 16 + rd * 4 + q;
      const float av = acts[p];
      f32x4 v[4];
      float s = 0.f, s2 = 0.f;
#pragma unroll
      for (int j = 0; j < 4; ++j) {
#pragma unroll
        for (int u = 0; u < 4; ++u) {
          v[j][u] = nvv[rd * 4 + j][u] + av * w4[j][u];
          s += v[j][u];
          s2 = fmaf(v[j][u], v[j][u], s2);
        }
      }
#pragma unroll
      for (int m = 1; m < 16; m <<= 1) { s += __shfl_xor(s, m); s2 += __shfl_xor(s2, m); }
      const float mu = s * (1.f / 256.f);
      const float var = fmaxf(s2 * (1.f / 256.f) - mu * mu, 0.f);
      const float rstd = 1.f / sqrtf(var + 1e-5f);
      short8 lo, hi;
#pragma unroll
      for (int j = 0; j < 4; ++j)
#pragma unroll
        for (int u = 0; u < 4; ++u) {
          const float hv = gelu_fast((v[j][u] - mu) * rstd * g1[j][u] + b1[j][u]);
          if (j < 2) lo[j * 4 + u] = (short)f2bf(hv);
          else       hi[(j - 2) * 4 + u] = (short)f2bf(hv);
        }
      *(short8*)&h1s[p * 264 + c * 16] = lo;
      *(short8*)&h1s[p * 264 + c * 16 + 8] = hi;
    }
  }
  __syncthreads();
  short8 afr[8];
#pragma unroll
  for (int ks = 0; ks < 8; ++ks)
    afr[ks] = *(const short8*)&h1s[(w * 16 + c) * 264 + ks * 32 + q * 8];
  f32x4 acc[16];
#pragma unroll
  for (int nt = 0; nt < 16; ++nt) {
    const float bz = pb2[nt * 16 + c];
    acc[nt] = (f32x4){bz, bz, bz, bz};
  }
  // ---- Phase B: 4 chunks of 64 N-rows; fully unrolled ----
#pragma unroll
  for (int ch = 0; ch < 4; ++ch) {
    __syncthreads();
#pragma unroll
    for (int i = 0; i < 8; ++i) {
      const int cidx = i * 256 + tid;
      const int n = cidx >> 5, kc = cidx & 31;
      *(i32x4*)&Bs[n * 264 + kc * 8] =
          *(const i32x4*)&pW2T[(size_t)(ch * 64 + n) * 256 + kc * 8];
    }
    __syncthreads();
#pragma unroll
    for (int t4 = 0; t4 < 4; ++t4) {
      const int nt = ch * 4 + t4;
#pragma unroll
      for (int ks = 0; ks < 8; ++ks) {
        const short8 bfr = *(const short8*)&Bs[(t4 * 16 + c) * 264 + ks * 32 + q * 8];
        acc[nt] = __builtin_amdgcn_mfma_f32_16x16x32_bf16(afr[ks], bfr, acc[nt], 0, 0, 0);
      }
    }
  }
  // ---- Phase C: LN2 per pair + pair-sum ----
  float g2v[16], b2v[16];
#pragma unroll
  for (int nt = 0; nt < 16; ++nt) {
    g2v[nt] = pln2_g[nt * 16 + c];
    b2v[nt] = pln2_b[nt * 16 + c];
  }
  float aggl[16];
#pragma unroll
  for (int nt = 0; nt < 16; ++nt) aggl[nt] = 0.f;
#pragma unroll
  for (int reg = 0; reg < 4; ++reg) {
    float s = 0.f, s2 = 0.f;
#pragma unroll
    for (int nt = 0; nt < 16; ++nt) {
      const float vv = acc[nt][reg];
      s += vv;
      s2 = fmaf(vv, vv, s2);
    }
#pragma unroll
    for (int m = 1; m < 16; m <<= 1) { s += __shfl_xor(s, m); s2 += __shfl_xor(s2, m); }
    const float mu = s * (1.f / 256.f);
    const float var = fmaxf(s2 * (1.f / 256.f) - mu * mu, 0.f);
    const float rstd = 1.f / sqrtf(var + 1e-5f);
#pragma unroll
    for (int nt = 0; nt < 16; ++nt) {
      const float vv = acc[nt][reg];
      aggl[nt] += (vv - mu) * rstd * g2v[nt] + b2v[nt];
    }
  }
#pragma unroll
  for (int nt = 0; nt < 16; ++nt) {
    float vs = aggl[nt];
    vs += __shfl_xor(vs, 16);
    vs += __shfl_xor(vs, 32);
    if (q == 0) aggbuf[w * 256 + nt * 16 + c] = vs;
  }
  __syncthreads();
  // ---- fused rho-LN over 256 ----
  const float v = aggbuf[tid] + aggbuf[256 + tid] + aggbuf[512 + tid] + aggbuf[768 + tid];
  float s = v, s2 = v * v;
  waveRed2(s, s2);
  if ((tid & 63) == 0) { red[(tid >> 6) * 2] = s; red[(tid >> 6) * 2 + 1] = s2; }
  __syncthreads();
  s = red[0] + red[2] + red[4] + red[6];
  s2 = red[1] + red[3] + red[5] + red[7];
  const float mu = s * (1.f / 256.f);
  const float var = fmaxf(s2 * (1.f / 256.f) - mu * mu, 0.f);
  const float rstd = 1.f / sqrtf(var + 1e-5f);
  rh[(size_t)t * 256 + tid] = f2bf((v - mu) * rstd * rln_g[tid] + rln_b[tid]);
}

// ---------------- launch ----------------
extern "C" void kernel_launch(void* const* d_in, const int* in_sizes, int n_in,
                              void* d_out, int out_size, void* d_ws, size_t ws_size,
                              hipStream_t stream) {
  const float* x = (const float*)d_in[0];
  const float* W_in = (const float*)d_in[1];
  const float* nv = (const float*)d_in[2];
  const float* Wr1 = (const float*)d_in[3];
  const float* Wr2 = (const float*)d_in[4];
  const float* rn_g = (const float*)d_in[5];
  const float* rn_b = (const float*)d_in[6];
  const float* pW1 = (const float*)d_in[7];
  const float* pb1 = (const float*)d_in[8];
  const float* pln1_g = (const float*)d_in[9];
  const float* pln1_b = (const float*)d_in[10];
  const float* pW2 = (const float*)d_in[11];
  const float* pb2 = (const float*)d_in[12];
  const float* pln2_g = (const float*)d_in[13];
  const float* pln2_b = (const float*)d_in[14];
  const float* rln_g = (const float*)d_in[15];
  const float* rln_b = (const float*)d_in[16];
  const float* rW1 = (const float*)d_in[17];
  const float* rb1 = (const float*)d_in[18];
  const float* rW2 = (const float*)d_in[19];
  const float* rb2 = (const float*)d_in[20];
  float* out = (float*)d_out;
  const int T = in_sizes[0] / 512;  // 4096

  float* ws = (float*)d_ws;
  float* xln = ws;    ws += (size_t)T * 512;
  float* h = ws;      ws += (size_t)T * 512;
  float* nvphi = ws;  ws += (size_t)2048 * 256;
  float* actb = ws;   ws += (size_t)T * 64;
  int* idx = (int*)ws;   ws += (size_t)T * 64;
  u16* scoresb = (u16*)ws; ws += (size_t)T * 2048 / 2;
  u16* hb = (u16*)ws;    ws += (size_t)T * 512 / 2;
  u16* Wr2b = (u16*)ws;  ws += (size_t)2048 * 512 / 2;
  u16* pW2T = (u16*)ws;  ws += (size_t)2048 * 256 / 2;
  u16* rh = (u16*)ws;    ws += (size_t)T * 256 / 2;
  u16* t1b = (u16*)ws;   ws += (size_t)T * 512 / 2;
  u16* rW1T = (u16*)ws;  ws += (size_t)512 * 256 / 2;
  u16* rW2T = (u16*)ws;  ws += (size_t)512 * 512 / 2;

  k_prep<<<7424, 256, 0, stream>>>(nv, pW1, pb1, nvphi, pW2, pW2T, rW1, rW1T,
                                   rW2, rW2T, Wr2, Wr2b);
  k_ln512<<<T, 256, 0, stream>>>(x, rn_g, rn_b, xln);
  gemm8f<2, true><<<dim3(512 / 128, T / 128), 256, 0, stream>>>(
      xln, Wr1, h, hb, T, 512, 512);
  gemm_mf<0, false, 1><<<dim3(2048 / 128, T / 64), 256, 0, stream>>>(
      hb, Wr2b, nullptr, scoresb, T, 2048, 512);
  k_topk_act<<<T, 256, 0, stream>>>(scoresb, h, Wr2, x, W_in, idx, actb);
  k_phi<<<T, 256, 0, stream>>>(nvphi, pW1, pln1_g, pln1_b, pW2T, pb2, pln2_g,
                               pln2_b, idx, actb, rln_g, rln_b, rh);
  gemm_mf<1, true, 1><<<dim3(512 / 128, T / 64), 256, 0, stream>>>(
      rh, rW1T, rb1, t1b, T, 512, 256);
  gemm_mf<0, true, 0><<<dim3(512 / 128, T / 64), 256, 0, stream>>>(
      t1b, rW2T, rb2, out, T, 512, 512);
}

// Round 13
// 483.769 us; speedup vs baseline: 1.1192x; 1.1192x over previous
//
#include <hip/hip_runtime.h>
#include <cstdint>
#include <cstddef>

typedef unsigned short u16;
typedef float f32x4 __attribute__((ext_vector_type(4)));
typedef short short8 __attribute__((ext_vector_type(8)));
typedef int i32x4 __attribute__((ext_vector_type(4)));

// ---------------- helpers ----------------

__device__ __forceinline__ float geluf(float v) {  // exact (libm erff)
  return 0.5f * v * (1.0f + erff(v * 0.70710678118654752440f));
}

// Abramowitz-Stegun 7.1.26: |err| <= 1.5e-7 abs.
__device__ __forceinline__ float erf_fast(float x) {
  const float ax = fabsf(x);
  const float t = __builtin_amdgcn_rcpf(fmaf(0.3275911f, ax, 1.0f));
  float p = fmaf(1.061405429f, t, -1.453152027f);
  p = fmaf(p, t, 1.421413741f);
  p = fmaf(p, t, -0.284496736f);
  p = fmaf(p, t, 0.254829592f);
  p = p * t;
  const float e = __expf(-ax * ax);
  const float r = fmaf(-p, e, 1.0f);
  return copysignf(r, x);
}
__device__ __forceinline__ float gelu_fast(float v) {
  return 0.5f * v * (1.0f + erf_fast(v * 0.70710678118654752440f));
}

__device__ __forceinline__ u16 f2bf(float f) {  // RNE fp32 -> bf16 bits
  unsigned u = __float_as_uint(f);
  u = (u + 0x7FFFu + ((u >> 16) & 1u)) >> 16;
  return (u16)u;
}
__device__ __forceinline__ float bf2f(u16 h) {
  return __uint_as_float(((unsigned)h) << 16);
}

__device__ __forceinline__ void waveRed2(float& s, float& s2) {
#pragma unroll
  for (int m = 1; m < 64; m <<= 1) {
    s += __shfl_xor(s, m);
    s2 += __shfl_xor(s2, m);
  }
}

// ---------------- fused prep: nvphi + converts + router-LN ----------------
// Block ranges:
//   [0,2048)       nvphi[n]   = nv[n]@pW1[:128] + pb1
//   [2048,2304)    pW2T[n][k] = bf16(pW2[k][n])
//   [2304,2816)    rW1T[n][k] = bf16(rW1[k][n])
//   [2816,3328)    rW2T[n][k] = bf16(rW2[k][n])
//   [3328,7424)    Wr2b       = bf16(Wr2)
//   [7424,7424+T)  xln[t]     = LN(x[t]) (fp32, score-critical)
__global__ __launch_bounds__(256) void k_prep(
    const float* __restrict__ nv, const float* __restrict__ pW1,
    const float* __restrict__ pb1, float* __restrict__ nvphi,
    const float* __restrict__ pW2, u16* __restrict__ pW2T,
    const float* __restrict__ rW1, u16* __restrict__ rW1T,
    const float* __restrict__ rW2, u16* __restrict__ rW2T,
    const float* __restrict__ Wr2, u16* __restrict__ Wr2b,
    const float* __restrict__ x, const float* __restrict__ rn_g,
    const float* __restrict__ rn_b, float* __restrict__ xln) {
  __shared__ float nvs[128];
  __shared__ float red[8];
  const int b = blockIdx.x, tid = threadIdx.x;
  if (b < 2048) {
    const int n = b;
    if (tid < 128) nvs[tid] = nv[n * 128 + tid];
    __syncthreads();
    float s = pb1[tid];
#pragma unroll 4
    for (int i = 0; i < 128; ++i) s = fmaf(nvs[i], pW1[i * 256 + tid], s);
    nvphi[n * 256 + tid] = s;
  } else if (b < 2304) {
    const int n = b - 2048;
    pW2T[n * 256 + tid] = f2bf(pW2[tid * 256 + n]);
  } else if (b < 2816) {
    const int n = b - 2304;
    if (tid < 256) rW1T[(size_t)n * 256 + tid] = f2bf(rW1[(size_t)tid * 512 + n]);
  } else if (b < 3328) {
    const int n = b - 2816;
    for (int k = tid; k < 512; k += 256)
      rW2T[(size_t)n * 512 + k] = f2bf(rW2[(size_t)k * 512 + n]);
  } else if (b < 7424) {
    const int i = (b - 3328) * 256 + tid;
    Wr2b[i] = f2bf(Wr2[i]);
  } else {
    const int t = b - 7424;
    const float v0 = x[(size_t)t * 512 + tid];
    const float v1 = x[(size_t)t * 512 + 256 + tid];
    float s = v0 + v1, s2 = v0 * v0 + v1 * v1;
    waveRed2(s, s2);
    if ((tid & 63) == 0) { red[(tid >> 6) * 2] = s; red[(tid >> 6) * 2 + 1] = s2; }
    __syncthreads();
    s = red[0] + red[2] + red[4] + red[6];
    s2 = red[1] + red[3] + red[5] + red[7];
    const float mu = s * (1.f / 512.f);
    const float var = fmaxf(s2 * (1.f / 512.f) - mu * mu, 0.f);
    const float rstd = 1.f / sqrtf(var + 1e-5f);
    xln[(size_t)t * 512 + tid] = (v0 - mu) * rstd * rn_g[tid] + rn_b[tid];
    xln[(size_t)t * 512 + 256 + tid] =
        (v1 - mu) * rstd * rn_g[tid + 256] + rn_b[tid + 256];
  }
}

// ---------------- 128x128 fp32 GEMM, C = act(A[M,K] @ B[N,K]^T) ----------------
template <int GMODE, bool BF16OUT>
__global__ __launch_bounds__(256) void gemm8f(const float* __restrict__ A,
                                              const float* __restrict__ B,
                                              float* __restrict__ C,
                                              u16* __restrict__ Cb, int M,
                                              int N, int K) {
  __shared__ float As[16][132];
  __shared__ float Bs[16][132];
  const int tid = threadIdx.x;
  const int tm = tid >> 4, tn = tid & 15;
  const int m0 = blockIdx.y * 128, n0 = blockIdx.x * 128;
  const int sr = tid >> 1, sk = (tid & 1) * 8;
  const float* gA = &A[(size_t)(m0 + sr) * K + sk];
  const float* gB = &B[(size_t)(n0 + sr) * K + sk];
  float acc[8][8] = {};
  for (int k0 = 0; k0 < K; k0 += 16) {
    const float4 a0 = *(const float4*)&gA[k0];
    const float4 a1 = *(const float4*)&gA[k0 + 4];
    const float4 b0 = *(const float4*)&gB[k0];
    const float4 b1 = *(const float4*)&gB[k0 + 4];
    __syncthreads();
    As[sk + 0][sr] = a0.x; As[sk + 1][sr] = a0.y; As[sk + 2][sr] = a0.z; As[sk + 3][sr] = a0.w;
    As[sk + 4][sr] = a1.x; As[sk + 5][sr] = a1.y; As[sk + 6][sr] = a1.z; As[sk + 7][sr] = a1.w;
    Bs[sk + 0][sr] = b0.x; Bs[sk + 1][sr] = b0.y; Bs[sk + 2][sr] = b0.z; Bs[sk + 3][sr] = b0.w;
    Bs[sk + 4][sr] = b1.x; Bs[sk + 5][sr] = b1.y; Bs[sk + 6][sr] = b1.z; Bs[sk + 7][sr] = b1.w;
    __syncthreads();
#pragma unroll
    for (int k = 0; k < 16; ++k) {
      float a[8], b[8];
      *(float4*)&a[0] = *(const float4*)&As[k][tm * 8];
      *(float4*)&a[4] = *(const float4*)&As[k][tm * 8 + 4];
      *(float4*)&b[0] = *(const float4*)&Bs[k][tn * 8];
      *(float4*)&b[4] = *(const float4*)&Bs[k][tn * 8 + 4];
#pragma unroll
      for (int i = 0; i < 8; ++i)
#pragma unroll
        for (int j = 0; j < 8; ++j) acc[i][j] = fmaf(a[i], b[j], acc[i][j]);
    }
  }
#pragma unroll
  for (int i = 0; i < 8; ++i) {
    float4 o0, o1;
    float* p0 = (float*)&o0;
    float* p1 = (float*)&o1;
#pragma unroll
    for (int j = 0; j < 4; ++j) {
      float xv = acc[i][j], yv = acc[i][j + 4];
      if (GMODE == 1) { xv = gelu_fast(xv); yv = gelu_fast(yv); }
      if (GMODE == 2) { xv = geluf(xv); yv = geluf(yv); }
      p0[j] = xv; p1[j] = yv;
    }
    const size_t off = (size_t)(m0 + tm * 8 + i) * N + n0 + tn * 8;
    *(float4*)&C[off] = o0;
    *(float4*)&C[off + 4] = o1;
    if (BF16OUT) {
      ushort4 u0, u1;
      u0.x = f2bf(p0[0]); u0.y = f2bf(p0[1]); u0.z = f2bf(p0[2]); u0.w = f2bf(p0[3]);
      u1.x = f2bf(p1[0]); u1.y = f2bf(p1[1]); u1.z = f2bf(p1[2]); u1.w = f2bf(p1[3]);
      *(ushort4*)&Cb[off] = u0;
      *(ushort4*)&Cb[off + 4] = u1;
    }
  }
}

// ---------------- MFMA GEMM: C = act(A[M,K] @ B[N,K]^T + bias) ----------------
template <int GMODE, bool BIAS, int OUT>
__global__ __launch_bounds__(256) void gemm_mf(const u16* __restrict__ Ahi,
                                               const u16* __restrict__ Bhi,
                                               const float* __restrict__ bias,
                                               void* __restrict__ Cp, int M,
                                               int N, int K) {
  constexpr int ASZ = 64 * 40;
  constexpr int BSZ = 128 * 40;
  __shared__ __align__(16) u16 smem[ASZ + BSZ];
  u16* sAh = smem;
  u16* sBh = smem + ASZ;

  const int tid = threadIdx.x;
  const int w = tid >> 6, lane = tid & 63;
  const int q = lane >> 4, c = lane & 15;
  const int m0 = blockIdx.y * 64, n0 = blockIdx.x * 128;
  const int ra = tid >> 2, ka = (tid & 3) * 8;
  const int rb = tid >> 1, kb = (tid & 1) * 16;
  const u16* gAh = Ahi + (size_t)(m0 + ra) * K + ka;
  const u16* gBh = Bhi + (size_t)(n0 + rb) * K + kb;

  f32x4 acc[8];
#pragma unroll
  for (int ct = 0; ct < 8; ++ct) {
    const float bv = BIAS ? bias[n0 + ct * 16 + c] : 0.f;
    acc[ct] = (f32x4){bv, bv, bv, bv};
  }

  for (int k0 = 0; k0 < K; k0 += 32) {
    const i32x4 vah = *(const i32x4*)(gAh + k0);
    const i32x4 vbh0 = *(const i32x4*)(gBh + k0);
    const i32x4 vbh1 = *(const i32x4*)(gBh + k0 + 8);
    __syncthreads();
    *(i32x4*)&sAh[ra * 40 + ka] = vah;
    *(i32x4*)&sBh[rb * 40 + kb] = vbh0;
    *(i32x4*)&sBh[rb * 40 + kb + 8] = vbh1;
    __syncthreads();
    const int abase = (w * 16 + c) * 40 + q * 8;
    const short8 ah = *(const short8*)&sAh[abase];
#pragma unroll
    for (int ct = 0; ct < 8; ++ct) {
      const int bbase = (ct * 16 + c) * 40 + q * 8;
      const short8 bh = *(const short8*)&sBh[bbase];
      acc[ct] = __builtin_amdgcn_mfma_f32_16x16x32_bf16(ah, bh, acc[ct], 0, 0, 0);
    }
  }
#pragma unroll
  for (int ct = 0; ct < 8; ++ct) {
#pragma unroll
    for (int reg = 0; reg < 4; ++reg) {
      float v = acc[ct][reg];
      if (GMODE == 1) v = gelu_fast(v);
      const size_t off = (size_t)(m0 + w * 16 + q * 4 + reg) * N + n0 + ct * 16 + c;
      if (OUT == 0) ((float*)Cp)[off] = v;
      else          ((u16*)Cp)[off] = f2bf(v);
    }
  }
}

// ---------------- fused: top-64 (approx+exact rescore) THEN act ----------------
// R11 version (coalesced lane-consecutive dots). R12's 16-lane sub-wave layout
// strided lanes 128B apart per instruction -> uncoalesced, FETCH +46%,
// 142->198us; reverted.
__global__ __launch_bounds__(256) void k_topk_act(
    const u16* __restrict__ scoresb, const float* __restrict__ h,
    const float* __restrict__ Wr2, const float* __restrict__ x,
    const float* __restrict__ W_in, int* __restrict__ idxout,
    float* __restrict__ act) {
  __shared__ float hs[512];
  __shared__ int redc[4];
  __shared__ int cand[160];
  __shared__ float cex[160];
  __shared__ int selidx[64];
  __shared__ unsigned ccnt, cg_cnt, ec;
  __shared__ int eqbuf[64];
  const int t = blockIdx.x, tid = threadIdx.x;
  hs[tid] = h[(size_t)t * 512 + tid];
  hs[tid + 256] = h[(size_t)t * 512 + 256 + tid];
  unsigned key[8];
#pragma unroll
  for (int j = 0; j < 8; ++j) {
    const unsigned u = (unsigned)scoresb[(size_t)t * 2048 + tid + 256 * j];
    key[j] = (u & 0x8000u) ? (0xFFFFu & ~u) : (u | 0x8000u);
  }
  if (tid == 0) ccnt = 0u;
  unsigned lo = 0u, hi = 0xFFFFu;
  while (lo < hi) {
    const unsigned mid = (lo + hi + 1u) >> 1;
    int c = 0;
#pragma unroll
    for (int j = 0; j < 8; ++j) c += (key[j] >= mid);
#pragma unroll
    for (int m = 1; m < 64; m <<= 1) c += __shfl_xor(c, m);
    if ((tid & 63) == 0) redc[tid >> 6] = c;
    __syncthreads();
    const int total = redc[0] + redc[1] + redc[2] + redc[3];
    __syncthreads();
    if (total >= 96) lo = mid; else hi = mid - 1;
  }
#pragma unroll
  for (int j = 0; j < 8; ++j) {
    if (key[j] >= lo) {
      const unsigned pos = atomicAdd(&ccnt, 1u);
      if (pos < 160u) cand[pos] = tid + 256 * j;
    }
  }
  __syncthreads();
  const int cnt = (int)(ccnt < 160u ? ccnt : 160u);
  // exact fp32 rescore of candidates (lane-consecutive, coalesced)
  const int wv = tid >> 6, l = tid & 63;
  for (int ci = wv; ci < cnt; ci += 4) {
    const float* Wr = Wr2 + (size_t)cand[ci] * 512;
    float s = 0.f;
#pragma unroll
    for (int j = 0; j < 8; ++j) s = fmaf(Wr[l + 64 * j], hs[l + 64 * j], s);
#pragma unroll
    for (int m = 1; m < 64; m <<= 1) s += __shfl_xor(s, m);
    if (l == 0) cex[ci] = s;
  }
  __syncthreads();
  // exact top-64 among cnt candidates
  unsigned k2 = 0u;
  int myidx = -1;
  const bool valid = tid < cnt;
  if (valid) {
    const unsigned u = __float_as_uint(cex[tid]);
    k2 = (u & 0x80000000u) ? ~u : (u | 0x80000000u);
    myidx = cand[tid];
  }
  if (tid == 0) { cg_cnt = 0u; ec = 0u; }
  unsigned lo2 = 0u, hi2 = 0xFFFFFFFFu;
  while (lo2 < hi2) {
    const unsigned mid = (unsigned)(((unsigned long long)lo2 + hi2 + 1ull) >> 1);
    int c = (valid && k2 >= mid) ? 1 : 0;
#pragma unroll
    for (int m = 1; m < 64; m <<= 1) c += __shfl_xor(c, m);
    if ((tid & 63) == 0) redc[tid >> 6] = c;
    __syncthreads();
    const int total = redc[0] + redc[1] + redc[2] + redc[3];
    __syncthreads();
    if (total >= 64) lo2 = mid; else hi2 = mid - 1;
  }
  if (valid && k2 > lo2) {
    const unsigned pos = atomicAdd(&cg_cnt, 1u);
    idxout[(size_t)t * 64 + pos] = myidx;
    selidx[pos] = myidx;
  } else if (valid && k2 == lo2) {
    const unsigned e = atomicAdd(&ec, 1u);
    if (e < 64u) eqbuf[e] = myidx;
  }
  __syncthreads();
  if (tid == 0) {
    const int cg = (int)cg_cnt;
    int ne = (int)ec; if (ne > 64) ne = 64;
    const int need = 64 - cg;
    for (int i = 1; i < ne; ++i) {
      const int v = eqbuf[i];
      int j = i - 1;
      while (j >= 0 && eqbuf[j] > v) { eqbuf[j + 1] = eqbuf[j]; --j; }
      eqbuf[j + 1] = v;
    }
    for (int i = 0; i < need; ++i) {
      idxout[(size_t)t * 64 + cg + i] = eqbuf[i];
      selidx[cg + i] = eqbuf[i];
    }
  }
  __syncthreads();
  // ---- Part 2: act (reuse hs for x) ----
  hs[tid] = x[(size_t)t * 512 + tid];
  hs[tid + 256] = x[(size_t)t * 512 + 256 + tid];
  __syncthreads();
  const float4 xa = *(const float4*)&hs[l * 8];
  const float4 xb = *(const float4*)&hs[l * 8 + 4];
  for (int qq = 0; qq < 16; ++qq) {
    const int k = wv * 16 + qq;
    const int n = selidx[k];
    const float* Wr = W_in + (size_t)n * 512 + l * 8;
    const float4 wa = *(const float4*)Wr;
    const float4 wb = *(const float4*)(Wr + 4);
    float s = wa.x * xa.x;
    s = fmaf(wa.y, xa.y, s); s = fmaf(wa.z, xa.z, s); s = fmaf(wa.w, xa.w, s);
    s = fmaf(wb.x, xb.x, s); s = fmaf(wb.y, xb.y, s);
    s = fmaf(wb.z, xb.z, s); s = fmaf(wb.w, xb.w, s);
#pragma unroll
    for (int m = 1; m < 64; m <<= 1) s += __shfl_xor(s, m);
    if (l == 0) act[(size_t)t * 64 + k] = gelu_fast(s);
  }
}

// ---------------- fused phi + rho-LN (one token per block) ----------------
// R9 Phase A (unroll 1 — R10's unroll-2 and R12's prefetch both raised VGPR),
// Phase B in 8 chunks of 32 N-rows, aggbuf aliased onto dead h1s.
// LDS ~51KB -> 3 blocks/CU if VGPR stays ~108 (vs R9's 72KB/2 blocks).
// All register-array indices compile-time (spill lesson R2/R5/R6).
__global__ __launch_bounds__(256, 1) void k_phi(
    const float* __restrict__ nvphi, const float* __restrict__ pW1,
    const float* __restrict__ pln1_g, const float* __restrict__ pln1_b,
    const u16* __restrict__ pW2T, const float* __restrict__ pb2,
    const float* __restrict__ pln2_g, const float* __restrict__ pln2_b,
    const int* __restrict__ idx, const float* __restrict__ act,
    const float* __restrict__ rln_g, const float* __restrict__ rln_b,
    u16* __restrict__ rh) {
  __shared__ __align__(16) u16 h1s[64 * 264];  // 33792B; aliased by aggbuf later
  __shared__ __align__(16) u16 Bs[32 * 264];   // 16896B
  __shared__ float red[8];
  __shared__ int idxs[64];
  __shared__ float acts[64];
  const int tid = threadIdx.x;
  const int t = blockIdx.x;
  const int w = tid >> 6, lane = tid & 63;
  const int q = lane >> 4, c = lane & 15;
  if (tid < 64) {
    idxs[tid] = idx[(size_t)t * 64 + tid];
    acts[tid] = act[(size_t)t * 64 + tid];
  }
  __syncthreads();
  // ---- Phase A (R9: unroll 1) ----
  {
    f32x4 w4[4], g1[4], b1[4];
#pragma unroll
    for (int j = 0; j < 4; ++j) {
      w4[j] = *(const f32x4*)&pW1[128 * 256 + c * 16 + j * 4];
      g1[j] = *(const f32x4*)&pln1_g[c * 16 + j * 4];
      b1[j] = *(const f32x4*)&pln1_b[c * 16 + j * 4];
    }
#pragma unroll 1
    for (int rd = 0; rd < 4; ++rd) {
      const int p = w * 16 + rd * 4 + q;
      const int n = idxs[p];
      const float av = acts[p];
      f32x4 v[4];
      float s = 0.f, s2 = 0.f;
#pragma unroll
      for (int j = 0; j < 4; ++j) {
        const f32x4 nv = *(const f32x4*)&nvphi[(size_t)n * 256 + c * 16 + j * 4];
#pragma unroll
        for (int u = 0; u < 4; ++u) {
          v[j][u] = nv[u] + av * w4[j][u];
          s += v[j][u];
          s2 = fmaf(v[j][u], v[j][u], s2);
        }
      }
#pragma unroll
      for (int m = 1; m < 16; m <<= 1) { s += __shfl_xor(s, m); s2 += __shfl_xor(s2, m); }
      const float mu = s * (1.f / 256.f);
      const float var = fmaxf(s2 * (1.f / 256.f) - mu * mu, 0.f);
      const float rstd = 1.f / sqrtf(var + 1e-5f);
      short8 lo, hi;
#pragma unroll
      for (int j = 0; j < 4; ++j)
#pragma unroll
        for (int u = 0; u < 4; ++u) {
          const float hv = gelu_fast((v[j][u] - mu) * rstd * g1[j][u] + b1[j][u]);
          if (j < 2) lo[j * 4 + u] = (short)f2bf(hv);
          else       hi[(j - 2) * 4 + u] = (short)f2bf(hv);
        }
      *(short8*)&h1s[p * 264 + c * 16] = lo;
      *(short8*)&h1s[p * 264 + c * 16 + 8] = hi;
    }
  }
  __syncthreads();
  short8 afr[8];
#pragma unroll
  for (int ks = 0; ks < 8; ++ks)
    afr[ks] = *(const short8*)&h1s[(w * 16 + c) * 264 + ks * 32 + q * 8];
  f32x4 acc[16];
#pragma unroll
  for (int nt = 0; nt < 16; ++nt) {
    const float bz = pb2[nt * 16 + c];
    acc[nt] = (f32x4){bz, bz, bz, bz};
  }
  // ---- Phase B: 8 chunks of 32 N-rows; fully unrolled (compile-time acc idx) ----
#pragma unroll
  for (int ch = 0; ch < 8; ++ch) {
    __syncthreads();
#pragma unroll
    for (int i = 0; i < 4; ++i) {
      const int cidx = i * 256 + tid;       // 0..1023 16B-chunks
      const int n = cidx >> 5, kc = cidx & 31;
      *(i32x4*)&Bs[n * 264 + kc * 8] =
          *(const i32x4*)&pW2T[(size_t)(ch * 32 + n) * 256 + kc * 8];
    }
    __syncthreads();
#pragma unroll
    for (int t4 = 0; t4 < 2; ++t4) {
      const int nt = ch * 2 + t4;
#pragma unroll
      for (int ks = 0; ks < 8; ++ks) {
        const short8 bfr = *(const short8*)&Bs[(t4 * 16 + c) * 264 + ks * 32 + q * 8];
        acc[nt] = __builtin_amdgcn_mfma_f32_16x16x32_bf16(afr[ks], bfr, acc[nt], 0, 0, 0);
      }
    }
  }
  // ---- Phase C: LN2 per pair + pair-sum ----
  float g2v[16], b2v[16];
#pragma unroll
  for (int nt = 0; nt < 16; ++nt) {
    g2v[nt] = pln2_g[nt * 16 + c];
    b2v[nt] = pln2_b[nt * 16 + c];
  }
  float aggl[16];
#pragma unroll
  for (int nt = 0; nt < 16; ++nt) aggl[nt] = 0.f;
#pragma unroll
  for (int reg = 0; reg < 4; ++reg) {
    float s = 0.f, s2 = 0.f;
#pragma unroll
    for (int nt = 0; nt < 16; ++nt) {
      const float vv = acc[nt][reg];
      s += vv;
      s2 = fmaf(vv, vv, s2);
    }
#pragma unroll
    for (int m = 1; m < 16; m <<= 1) { s += __shfl_xor(s, m); s2 += __shfl_xor(s2, m); }
    const float mu = s * (1.f / 256.f);
    const float var = fmaxf(s2 * (1.f / 256.f) - mu * mu, 0.f);
    const float rstd = 1.f / sqrtf(var + 1e-5f);
#pragma unroll
    for (int nt = 0; nt < 16; ++nt) {
      const float vv = acc[nt][reg];
      aggl[nt] += (vv - mu) * rstd * g2v[nt] + b2v[nt];
    }
  }
  // h1s dead (afr loaded before Phase B's first barrier) -> alias aggbuf
  float* aggbuf = (float*)h1s;  // [4][256]
#pragma unroll
  for (int nt = 0; nt < 16; ++nt) {
    float vs = aggl[nt];
    vs += __shfl_xor(vs, 16);
    vs += __shfl_xor(vs, 32);
    if (q == 0) aggbuf[w * 256 + nt * 16 + c] = vs;
  }
  __syncthreads();
  // ---- fused rho-LN over 256 ----
  const float v = aggbuf[tid] + aggbuf[256 + tid] + aggbuf[512 + tid] + aggbuf[768 + tid];
  float s = v, s2 = v * v;
  waveRed2(s, s2);
  if ((tid & 63) == 0) { red[(tid >> 6) * 2] = s; red[(tid >> 6) * 2 + 1] = s2; }
  __syncthreads();
  s = red[0] + red[2] + red[4] + red[6];
  s2 = red[1] + red[3] + red[5] + red[7];
  const float mu = s * (1.f / 256.f);
  const float var = fmaxf(s2 * (1.f / 256.f) - mu * mu, 0.f);
  const float rstd = 1.f / sqrtf(var + 1e-5f);
  rh[(size_t)t * 256 + tid] = f2bf((v - mu) * rstd * rln_g[tid] + rln_b[tid]);
}

// ---------------- launch ----------------
extern "C" void kernel_launch(void* const* d_in, const int* in_sizes, int n_in,
                              void* d_out, int out_size, void* d_ws, size_t ws_size,
                              hipStream_t stream) {
  const float* x = (const float*)d_in[0];
  const float* W_in = (const float*)d_in[1];
  const float* nv = (const float*)d_in[2];
  const float* Wr1 = (const float*)d_in[3];
  const float* Wr2 = (const float*)d_in[4];
  const float* rn_g = (const float*)d_in[5];
  const float* rn_b = (const float*)d_in[6];
  const float* pW1 = (const float*)d_in[7];
  const float* pb1 = (const float*)d_in[8];
  const float* pln1_g = (const float*)d_in[9];
  const float* pln1_b = (const float*)d_in[10];
  const float* pW2 = (const float*)d_in[11];
  const float* pb2 = (const float*)d_in[12];
  const float* pln2_g = (const float*)d_in[13];
  const float* pln2_b = (const float*)d_in[14];
  const float* rln_g = (const float*)d_in[15];
  const float* rln_b = (const float*)d_in[16];
  const float* rW1 = (const float*)d_in[17];
  const float* rb1 = (const float*)d_in[18];
  const float* rW2 = (const float*)d_in[19];
  const float* rb2 = (const float*)d_in[20];
  float* out = (float*)d_out;
  const int T = in_sizes[0] / 512;  // 4096

  float* ws = (float*)d_ws;
  float* xln = ws;    ws += (size_t)T * 512;
  float* h = ws;      ws += (size_t)T * 512;
  float* nvphi = ws;  ws += (size_t)2048 * 256;
  float* actb = ws;   ws += (size_t)T * 64;
  int* idx = (int*)ws;   ws += (size_t)T * 64;
  u16* scoresb = (u16*)ws; ws += (size_t)T * 2048 / 2;
  u16* hb = (u16*)ws;    ws += (size_t)T * 512 / 2;
  u16* Wr2b = (u16*)ws;  ws += (size_t)2048 * 512 / 2;
  u16* pW2T = (u16*)ws;  ws += (size_t)2048 * 256 / 2;
  u16* rh = (u16*)ws;    ws += (size_t)T * 256 / 2;
  u16* t1b = (u16*)ws;   ws += (size_t)T * 512 / 2;
  u16* rW1T = (u16*)ws;  ws += (size_t)512 * 256 / 2;
  u16* rW2T = (u16*)ws;  ws += (size_t)512 * 512 / 2;

  // 1: fused prep (nvphi + weight converts + router LN)
  k_prep<<<7424 + T, 256, 0, stream>>>(nv, pW1, pb1, nvphi, pW2, pW2T, rW1,
                                       rW1T, rW2, rW2T, Wr2, Wr2b, x, rn_g,
                                       rn_b, xln);
  // 2: h = gelu(xln @ Wr1^T) exact fp32 (+ bf16 copy)
  gemm8f<2, true><<<dim3(512 / 128, T / 128), 256, 0, stream>>>(
      xln, Wr1, h, hb, T, 512, 512);
  // 3: approx scores (bf16 MFMA)
  gemm_mf<0, false, 1><<<dim3(2048 / 128, T / 64), 256, 0, stream>>>(
      hb, Wr2b, nullptr, scoresb, T, 2048, 512);
  // 4: top-64 (exact rescore) + act, fused
  k_topk_act<<<T, 256, 0, stream>>>(scoresb, h, Wr2, x, W_in, idx, actb);
  // 5: phi + rho-LN, fused
  k_phi<<<T, 256, 0, stream>>>(nvphi, pW1, pln1_g, pln1_b, pW2T, pb2, pln2_g,
                               pln2_b, idx, actb, rln_g, rln_b, rh);
  // 6-7: rho (plain bf16 MFMA)
  gemm_mf<1, true, 1><<<dim3(512 / 128, T / 64), 256, 0, stream>>>(
      rh, rW1T, rb1, t1b, T, 512, 256);
  gemm_mf<0, true, 0><<<dim3(512 / 128, T / 64), 256, 0, stream>>>(
      t1b, rW2T, rb2, out, T, 512, 512);
}

// Round 14
// 444.862 us; speedup vs baseline: 1.2171x; 1.0875x over previous
//
#include <hip/hip_runtime.h>
#include <cstdint>
#include <cstddef>

typedef unsigned short u16;
typedef float f32x4 __attribute__((ext_vector_type(4)));
typedef short short8 __attribute__((ext_vector_type(8)));
typedef int i32x4 __attribute__((ext_vector_type(4)));

// ---------------- helpers ----------------

__device__ __forceinline__ float geluf(float v) {  // exact (libm erff)
  return 0.5f * v * (1.0f + erff(v * 0.70710678118654752440f));
}

// Abramowitz-Stegun 7.1.26: |err| <= 1.5e-7 abs.
__device__ __forceinline__ float erf_fast(float x) {
  const float ax = fabsf(x);
  const float t = __builtin_amdgcn_rcpf(fmaf(0.3275911f, ax, 1.0f));
  float p = fmaf(1.061405429f, t, -1.453152027f);
  p = fmaf(p, t, 1.421413741f);
  p = fmaf(p, t, -0.284496736f);
  p = fmaf(p, t, 0.254829592f);
  p = p * t;
  const float e = __expf(-ax * ax);
  const float r = fmaf(-p, e, 1.0f);
  return copysignf(r, x);
}
__device__ __forceinline__ float gelu_fast(float v) {
  return 0.5f * v * (1.0f + erf_fast(v * 0.70710678118654752440f));
}

__device__ __forceinline__ u16 f2bf(float f) {  // RNE fp32 -> bf16 bits
  unsigned u = __float_as_uint(f);
  u = (u + 0x7FFFu + ((u >> 16) & 1u)) >> 16;
  return (u16)u;
}
__device__ __forceinline__ float bf2f(u16 h) {
  return __uint_as_float(((unsigned)h) << 16);
}

__device__ __forceinline__ void waveRed2(float& s, float& s2) {
#pragma unroll
  for (int m = 1; m < 64; m <<= 1) {
    s += __shfl_xor(s, m);
    s2 += __shfl_xor(s2, m);
  }
}

// ---------------- fused prep: nvphi + converts + router-LN ----------------
__global__ __launch_bounds__(256) void k_prep(
    const float* __restrict__ nv, const float* __restrict__ pW1,
    const float* __restrict__ pb1, float* __restrict__ nvphi,
    const float* __restrict__ pW2, u16* __restrict__ pW2T,
    const float* __restrict__ rW1, u16* __restrict__ rW1T,
    const float* __restrict__ rW2, u16* __restrict__ rW2T,
    const float* __restrict__ Wr2, u16* __restrict__ Wr2b,
    const float* __restrict__ x, const float* __restrict__ rn_g,
    const float* __restrict__ rn_b, float* __restrict__ xln) {
  __shared__ float nvs[128];
  __shared__ float red[8];
  const int b = blockIdx.x, tid = threadIdx.x;
  if (b < 2048) {
    const int n = b;
    if (tid < 128) nvs[tid] = nv[n * 128 + tid];
    __syncthreads();
    float s = pb1[tid];
#pragma unroll 4
    for (int i = 0; i < 128; ++i) s = fmaf(nvs[i], pW1[i * 256 + tid], s);
    nvphi[n * 256 + tid] = s;
  } else if (b < 2304) {
    const int n = b - 2048;
    pW2T[n * 256 + tid] = f2bf(pW2[tid * 256 + n]);
  } else if (b < 2816) {
    const int n = b - 2304;
    if (tid < 256) rW1T[(size_t)n * 256 + tid] = f2bf(rW1[(size_t)tid * 512 + n]);
  } else if (b < 3328) {
    const int n = b - 2816;
    for (int k = tid; k < 512; k += 256)
      rW2T[(size_t)n * 512 + k] = f2bf(rW2[(size_t)k * 512 + n]);
  } else if (b < 7424) {
    const int i = (b - 3328) * 256 + tid;
    Wr2b[i] = f2bf(Wr2[i]);
  } else {
    const int t = b - 7424;
    const float v0 = x[(size_t)t * 512 + tid];
    const float v1 = x[(size_t)t * 512 + 256 + tid];
    float s = v0 + v1, s2 = v0 * v0 + v1 * v1;
    waveRed2(s, s2);
    if ((tid & 63) == 0) { red[(tid >> 6) * 2] = s; red[(tid >> 6) * 2 + 1] = s2; }
    __syncthreads();
    s = red[0] + red[2] + red[4] + red[6];
    s2 = red[1] + red[3] + red[5] + red[7];
    const float mu = s * (1.f / 512.f);
    const float var = fmaxf(s2 * (1.f / 512.f) - mu * mu, 0.f);
    const float rstd = 1.f / sqrtf(var + 1e-5f);
    xln[(size_t)t * 512 + tid] = (v0 - mu) * rstd * rn_g[tid] + rn_b[tid];
    xln[(size_t)t * 512 + 256 + tid] =
        (v1 - mu) * rstd * rn_g[tid + 256] + rn_b[tid + 256];
  }
}

// ---------------- 128x128 fp32 GEMM, C = act(A[M,K] @ B[N,K]^T) ----------------
template <int GMODE, bool BF16OUT>
__global__ __launch_bounds__(256) void gemm8f(const float* __restrict__ A,
                                              const float* __restrict__ B,
                                              float* __restrict__ C,
                                              u16* __restrict__ Cb, int M,
                                              int N, int K) {
  __shared__ float As[16][132];
  __shared__ float Bs[16][132];
  const int tid = threadIdx.x;
  const int tm = tid >> 4, tn = tid & 15;
  const int m0 = blockIdx.y * 128, n0 = blockIdx.x * 128;
  const int sr = tid >> 1, sk = (tid & 1) * 8;
  const float* gA = &A[(size_t)(m0 + sr) * K + sk];
  const float* gB = &B[(size_t)(n0 + sr) * K + sk];
  float acc[8][8] = {};
  for (int k0 = 0; k0 < K; k0 += 16) {
    const float4 a0 = *(const float4*)&gA[k0];
    const float4 a1 = *(const float4*)&gA[k0 + 4];
    const float4 b0 = *(const float4*)&gB[k0];
    const float4 b1 = *(const float4*)&gB[k0 + 4];
    __syncthreads();
    As[sk + 0][sr] = a0.x; As[sk + 1][sr] = a0.y; As[sk + 2][sr] = a0.z; As[sk + 3][sr] = a0.w;
    As[sk + 4][sr] = a1.x; As[sk + 5][sr] = a1.y; As[sk + 6][sr] = a1.z; As[sk + 7][sr] = a1.w;
    Bs[sk + 0][sr] = b0.x; Bs[sk + 1][sr] = b0.y; Bs[sk + 2][sr] = b0.z; Bs[sk + 3][sr] = b0.w;
    Bs[sk + 4][sr] = b1.x; Bs[sk + 5][sr] = b1.y; Bs[sk + 6][sr] = b1.z; Bs[sk + 7][sr] = b1.w;
    __syncthreads();
#pragma unroll
    for (int k = 0; k < 16; ++k) {
      float a[8], b[8];
      *(float4*)&a[0] = *(const float4*)&As[k][tm * 8];
      *(float4*)&a[4] = *(const float4*)&As[k][tm * 8 + 4];
      *(float4*)&b[0] = *(const float4*)&Bs[k][tn * 8];
      *(float4*)&b[4] = *(const float4*)&Bs[k][tn * 8 + 4];
#pragma unroll
      for (int i = 0; i < 8; ++i)
#pragma unroll
        for (int j = 0; j < 8; ++j) acc[i][j] = fmaf(a[i], b[j], acc[i][j]);
    }
  }
#pragma unroll
  for (int i = 0; i < 8; ++i) {
    float4 o0, o1;
    float* p0 = (float*)&o0;
    float* p1 = (float*)&o1;
#pragma unroll
    for (int j = 0; j < 4; ++j) {
      float xv = acc[i][j], yv = acc[i][j + 4];
      if (GMODE == 1) { xv = gelu_fast(xv); yv = gelu_fast(yv); }
      if (GMODE == 2) { xv = geluf(xv); yv = geluf(yv); }
      p0[j] = xv; p1[j] = yv;
    }
    const size_t off = (size_t)(m0 + tm * 8 + i) * N + n0 + tn * 8;
    *(float4*)&C[off] = o0;
    *(float4*)&C[off + 4] = o1;
    if (BF16OUT) {
      ushort4 u0, u1;
      u0.x = f2bf(p0[0]); u0.y = f2bf(p0[1]); u0.z = f2bf(p0[2]); u0.w = f2bf(p0[3]);
      u1.x = f2bf(p1[0]); u1.y = f2bf(p1[1]); u1.z = f2bf(p1[2]); u1.w = f2bf(p1[3]);
      *(ushort4*)&Cb[off] = u0;
      *(ushort4*)&Cb[off + 4] = u1;
    }
  }
}

// ---------------- MFMA GEMM: C = act(A[M,K] @ B[N,K]^T + bias) ----------------
template <int GMODE, bool BIAS, int OUT>
__global__ __launch_bounds__(256) void gemm_mf(const u16* __restrict__ Ahi,
                                               const u16* __restrict__ Bhi,
                                               const float* __restrict__ bias,
                                               void* __restrict__ Cp, int M,
                                               int N, int K) {
  constexpr int ASZ = 64 * 40;
  constexpr int BSZ = 128 * 40;
  __shared__ __align__(16) u16 smem[ASZ + BSZ];
  u16* sAh = smem;
  u16* sBh = smem + ASZ;

  const int tid = threadIdx.x;
  const int w = tid >> 6, lane = tid & 63;
  const int q = lane >> 4, c = lane & 15;
  const int m0 = blockIdx.y * 64, n0 = blockIdx.x * 128;
  const int ra = tid >> 2, ka = (tid & 3) * 8;
  const int rb = tid >> 1, kb = (tid & 1) * 16;
  const u16* gAh = Ahi + (size_t)(m0 + ra) * K + ka;
  const u16* gBh = Bhi + (size_t)(n0 + rb) * K + kb;

  f32x4 acc[8];
#pragma unroll
  for (int ct = 0; ct < 8; ++ct) {
    const float bv = BIAS ? bias[n0 + ct * 16 + c] : 0.f;
    acc[ct] = (f32x4){bv, bv, bv, bv};
  }

  for (int k0 = 0; k0 < K; k0 += 32) {
    const i32x4 vah = *(const i32x4*)(gAh + k0);
    const i32x4 vbh0 = *(const i32x4*)(gBh + k0);
    const i32x4 vbh1 = *(const i32x4*)(gBh + k0 + 8);
    __syncthreads();
    *(i32x4*)&sAh[ra * 40 + ka] = vah;
    *(i32x4*)&sBh[rb * 40 + kb] = vbh0;
    *(i32x4*)&sBh[rb * 40 + kb + 8] = vbh1;
    __syncthreads();
    const int abase = (w * 16 + c) * 40 + q * 8;
    const short8 ah = *(const short8*)&sAh[abase];
#pragma unroll
    for (int ct = 0; ct < 8; ++ct) {
      const int bbase = (ct * 16 + c) * 40 + q * 8;
      const short8 bh = *(const short8*)&sBh[bbase];
      acc[ct] = __builtin_amdgcn_mfma_f32_16x16x32_bf16(ah, bh, acc[ct], 0, 0, 0);
    }
  }
#pragma unroll
  for (int ct = 0; ct < 8; ++ct) {
#pragma unroll
    for (int reg = 0; reg < 4; ++reg) {
      float v = acc[ct][reg];
      if (GMODE == 1) v = gelu_fast(v);
      const size_t off = (size_t)(m0 + w * 16 + q * 4 + reg) * N + n0 + ct * 16 + c;
      if (OUT == 0) ((float*)Cp)[off] = v;
      else          ((u16*)Cp)[off] = f2bf(v);
    }
  }
}

// ---------------- fused: top-64 (approx+exact rescore) THEN act ----------------
// Barrier diet vs R13: approx radix uses double-buffered redc (1 barrier/iter,
// 16 total); exact select is RANK-BASED (zero barriers vs 64): thread i's rank
// = #{j: s_j>s_i || (s_j==s_i && idx_j<idx_i)} over <=160 LDS-broadcast
// scores. rank<64 <=> member of np's top-64 set (strict total order), and all
// downstream ops sum over k, so set-identity suffices.
__global__ __launch_bounds__(256) void k_topk_act(
    const u16* __restrict__ scoresb, const float* __restrict__ h,
    const float* __restrict__ Wr2, const float* __restrict__ x,
    const float* __restrict__ W_in, int* __restrict__ idxout,
    float* __restrict__ act) {
  __shared__ float hs[512];
  __shared__ int redc[2][4];
  __shared__ int cand[160];
  __shared__ float cex[160];
  __shared__ int selidx[64];
  __shared__ unsigned ccnt;
  const int t = blockIdx.x, tid = threadIdx.x;
  hs[tid] = h[(size_t)t * 512 + tid];
  hs[tid + 256] = h[(size_t)t * 512 + 256 + tid];
  unsigned key[8];
#pragma unroll
  for (int j = 0; j < 8; ++j) {
    const unsigned u = (unsigned)scoresb[(size_t)t * 2048 + tid + 256 * j];
    key[j] = (u & 0x8000u) ? (0xFFFFu & ~u) : (u | 0x8000u);
  }
  if (tid == 0) ccnt = 0u;
  // approx radix select (16 bits, 1 barrier/iter via double buffer)
  unsigned lo = 0u, hi = 0xFFFFu;
  int pb = 0;
  while (lo < hi) {
    const unsigned mid = (lo + hi + 1u) >> 1;
    int c = 0;
#pragma unroll
    for (int j = 0; j < 8; ++j) c += (key[j] >= mid);
#pragma unroll
    for (int m = 1; m < 64; m <<= 1) c += __shfl_xor(c, m);
    if ((tid & 63) == 0) redc[pb][tid >> 6] = c;
    __syncthreads();
    const int total = redc[pb][0] + redc[pb][1] + redc[pb][2] + redc[pb][3];
    if (total >= 96) lo = mid; else hi = mid - 1;
    pb ^= 1;
  }
#pragma unroll
  for (int j = 0; j < 8; ++j) {
    if (key[j] >= lo) {
      const unsigned pos = atomicAdd(&ccnt, 1u);
      if (pos < 160u) cand[pos] = tid + 256 * j;
    }
  }
  __syncthreads();
  const int cnt = (int)(ccnt < 160u ? ccnt : 160u);
  // exact fp32 rescore of candidates (lane-consecutive, coalesced — R11)
  const int wv = tid >> 6, l = tid & 63;
  for (int ci = wv; ci < cnt; ci += 4) {
    const float* Wr = Wr2 + (size_t)cand[ci] * 512;
    float s = 0.f;
#pragma unroll
    for (int j = 0; j < 8; ++j) s = fmaf(Wr[l + 64 * j], hs[l + 64 * j], s);
#pragma unroll
    for (int m = 1; m < 64; m <<= 1) s += __shfl_xor(s, m);
    if (l == 0) cex[ci] = s;
  }
  __syncthreads();
  // rank-based exact top-64 (no barriers in loop; LDS broadcast reads)
  if (tid < cnt) {
    const float my = cex[tid];
    const int myi = cand[tid];
    int rank = 0;
    for (int j = 0; j < cnt; ++j) {
      const float oj = cex[j];
      const int oi = cand[j];
      rank += (oj > my) || (oj == my && oi < myi);
    }
    if (rank < 64) {
      selidx[rank] = myi;
      idxout[(size_t)t * 64 + rank] = myi;
    }
  }
  __syncthreads();
  // ---- Part 2: act (reuse hs for x) ----
  hs[tid] = x[(size_t)t * 512 + tid];
  hs[tid + 256] = x[(size_t)t * 512 + 256 + tid];
  __syncthreads();
  const float4 xa = *(const float4*)&hs[l * 8];
  const float4 xb = *(const float4*)&hs[l * 8 + 4];
  for (int qq = 0; qq < 16; ++qq) {
    const int k = wv * 16 + qq;
    const int n = selidx[k];
    const float* Wr = W_in + (size_t)n * 512 + l * 8;
    const float4 wa = *(const float4*)Wr;
    const float4 wb = *(const float4*)(Wr + 4);
    float s = wa.x * xa.x;
    s = fmaf(wa.y, xa.y, s); s = fmaf(wa.z, xa.z, s); s = fmaf(wa.w, xa.w, s);
    s = fmaf(wb.x, xb.x, s); s = fmaf(wb.y, xb.y, s);
    s = fmaf(wb.z, xb.z, s); s = fmaf(wb.w, xb.w, s);
#pragma unroll
    for (int m = 1; m < 64; m <<= 1) s += __shfl_xor(s, m);
    if (l == 0) act[(size_t)t * 64 + k] = gelu_fast(s);
  }
}

// ---------------- fused phi + rho-LN (one token per block) ----------------
// R13 version (registers cap occupancy at 2 blocks/CU: 112 VGPR + 64 AGPR).
__global__ __launch_bounds__(256, 1) void k_phi(
    const float* __restrict__ nvphi, const float* __restrict__ pW1,
    const float* __restrict__ pln1_g, const float* __restrict__ pln1_b,
    const u16* __restrict__ pW2T, const float* __restrict__ pb2,
    const float* __restrict__ pln2_g, const float* __restrict__ pln2_b,
    const int* __restrict__ idx, const float* __restrict__ act,
    const float* __restrict__ rln_g, const float* __restrict__ rln_b,
    u16* __restrict__ rh) {
  __shared__ __align__(16) u16 h1s[64 * 264];
  __shared__ __align__(16) u16 Bs[32 * 264];
  __shared__ float red[8];
  __shared__ int idxs[64];
  __shared__ float acts[64];
  const int tid = threadIdx.x;
  const int t = blockIdx.x;
  const int w = tid >> 6, lane = tid & 63;
  const int q = lane >> 4, c = lane & 15;
  if (tid < 64) {
    idxs[tid] = idx[(size_t)t * 64 + tid];
    acts[tid] = act[(size_t)t * 64 + tid];
  }
  __syncthreads();
  // ---- Phase A ----
  {
    f32x4 w4[4], g1[4], b1[4];
#pragma unroll
    for (int j = 0; j < 4; ++j) {
      w4[j] = *(const f32x4*)&pW1[128 * 256 + c * 16 + j * 4];
      g1[j] = *(const f32x4*)&pln1_g[c * 16 + j * 4];
      b1[j] = *(const f32x4*)&pln1_b[c * 16 + j * 4];
    }
#pragma unroll 1
    for (int rd = 0; rd < 4; ++rd) {
      const int p = w * 16 + rd * 4 + q;
      const int n = idxs[p];
      const float av = acts[p];
      f32x4 v[4];
      float s = 0.f, s2 = 0.f;
#pragma unroll
      for (int j = 0; j < 4; ++j) {
        const f32x4 nv = *(const f32x4*)&nvphi[(size_t)n * 256 + c * 16 + j * 4];
#pragma unroll
        for (int u = 0; u < 4; ++u) {
          v[j][u] = nv[u] + av * w4[j][u];
          s += v[j][u];
          s2 = fmaf(v[j][u], v[j][u], s2);
        }
      }
#pragma unroll
      for (int m = 1; m < 16; m <<= 1) { s += __shfl_xor(s, m); s2 += __shfl_xor(s2, m); }
      const float mu = s * (1.f / 256.f);
      const float var = fmaxf(s2 * (1.f / 256.f) - mu * mu, 0.f);
      const float rstd = 1.f / sqrtf(var + 1e-5f);
      short8 lo, hi;
#pragma unroll
      for (int j = 0; j < 4; ++j)
#pragma unroll
        for (int u = 0; u < 4; ++u) {
          const float hv = gelu_fast((v[j][u] - mu) * rstd * g1[j][u] + b1[j][u]);
          if (j < 2) lo[j * 4 + u] = (short)f2bf(hv);
          else       hi[(j - 2) * 4 + u] = (short)f2bf(hv);
        }
      *(short8*)&h1s[p * 264 + c * 16] = lo;
      *(short8*)&h1s[p * 264 + c * 16 + 8] = hi;
    }
  }
  __syncthreads();
  short8 afr[8];
#pragma unroll
  for (int ks = 0; ks < 8; ++ks)
    afr[ks] = *(const short8*)&h1s[(w * 16 + c) * 264 + ks * 32 + q * 8];
  f32x4 acc[16];
#pragma unroll
  for (int nt = 0; nt < 16; ++nt) {
    const float bz = pb2[nt * 16 + c];
    acc[nt] = (f32x4){bz, bz, bz, bz};
  }
  // ---- Phase B: 8 chunks of 32 N-rows; fully unrolled ----
#pragma unroll
  for (int ch = 0; ch < 8; ++ch) {
    __syncthreads();
#pragma unroll
    for (int i = 0; i < 4; ++i) {
      const int cidx = i * 256 + tid;
      const int n = cidx >> 5, kc = cidx & 31;
      *(i32x4*)&Bs[n * 264 + kc * 8] =
          *(const i32x4*)&pW2T[(size_t)(ch * 32 + n) * 256 + kc * 8];
    }
    __syncthreads();
#pragma unroll
    for (int t4 = 0; t4 < 2; ++t4) {
      const int nt = ch * 2 + t4;
#pragma unroll
      for (int ks = 0; ks < 8; ++ks) {
        const short8 bfr = *(const short8*)&Bs[(t4 * 16 + c) * 264 + ks * 32 + q * 8];
        acc[nt] = __builtin_amdgcn_mfma_f32_16x16x32_bf16(afr[ks], bfr, acc[nt], 0, 0, 0);
      }
    }
  }
  // ---- Phase C: LN2 per pair + pair-sum ----
  float g2v[16], b2v[16];
#pragma unroll
  for (int nt = 0; nt < 16; ++nt) {
    g2v[nt] = pln2_g[nt * 16 + c];
    b2v[nt] = pln2_b[nt * 16 + c];
  }
  float aggl[16];
#pragma unroll
  for (int nt = 0; nt < 16; ++nt) aggl[nt] = 0.f;
#pragma unroll
  for (int reg = 0; reg < 4; ++reg) {
    float s = 0.f, s2 = 0.f;
#pragma unroll
    for (int nt = 0; nt < 16; ++nt) {
      const float vv = acc[nt][reg];
      s += vv;
      s2 = fmaf(vv, vv, s2);
    }
#pragma unroll
    for (int m = 1; m < 16; m <<= 1) { s += __shfl_xor(s, m); s2 += __shfl_xor(s2, m); }
    const float mu = s * (1.f / 256.f);
    const float var = fmaxf(s2 * (1.f / 256.f) - mu * mu, 0.f);
    const float rstd = 1.f / sqrtf(var + 1e-5f);
#pragma unroll
    for (int nt = 0; nt < 16; ++nt) {
      const float vv = acc[nt][reg];
      aggl[nt] += (vv - mu) * rstd * g2v[nt] + b2v[nt];
    }
  }
  // h1s dead -> alias aggbuf
  float* aggbuf = (float*)h1s;  // [4][256]
#pragma unroll
  for (int nt = 0; nt < 16; ++nt) {
    float vs = aggl[nt];
    vs += __shfl_xor(vs, 16);
    vs += __shfl_xor(vs, 32);
    if (q == 0) aggbuf[w * 256 + nt * 16 + c] = vs;
  }
  __syncthreads();
  // ---- fused rho-LN over 256 ----
  const float v = aggbuf[tid] + aggbuf[256 + tid] + aggbuf[512 + tid] + aggbuf[768 + tid];
  float s = v, s2 = v * v;
  waveRed2(s, s2);
  if ((tid & 63) == 0) { red[(tid >> 6) * 2] = s; red[(tid >> 6) * 2 + 1] = s2; }
  __syncthreads();
  s = red[0] + red[2] + red[4] + red[6];
  s2 = red[1] + red[3] + red[5] + red[7];
  const float mu = s * (1.f / 256.f);
  const float var = fmaxf(s2 * (1.f / 256.f) - mu * mu, 0.f);
  const float rstd = 1.f / sqrtf(var + 1e-5f);
  rh[(size_t)t * 256 + tid] = f2bf((v - mu) * rstd * rln_g[tid] + rln_b[tid]);
}

// ---------------- launch ----------------
extern "C" void kernel_launch(void* const* d_in, const int* in_sizes, int n_in,
                              void* d_out, int out_size, void* d_ws, size_t ws_size,
                              hipStream_t stream) {
  const float* x = (const float*)d_in[0];
  const float* W_in = (const float*)d_in[1];
  const float* nv = (const float*)d_in[2];
  const float* Wr1 = (const float*)d_in[3];
  const float* Wr2 = (const float*)d_in[4];
  const float* rn_g = (const float*)d_in[5];
  const float* rn_b = (const float*)d_in[6];
  const float* pW1 = (const float*)d_in[7];
  const float* pb1 = (const float*)d_in[8];
  const float* pln1_g = (const float*)d_in[9];
  const float* pln1_b = (const float*)d_in[10];
  const float* pW2 = (const float*)d_in[11];
  const float* pb2 = (const float*)d_in[12];
  const float* pln2_g = (const float*)d_in[13];
  const float* pln2_b = (const float*)d_in[14];
  const float* rln_g = (const float*)d_in[15];
  const float* rln_b = (const float*)d_in[16];
  const float* rW1 = (const float*)d_in[17];
  const float* rb1 = (const float*)d_in[18];
  const float* rW2 = (const float*)d_in[19];
  const float* rb2 = (const float*)d_in[20];
  float* out = (float*)d_out;
  const int T = in_sizes[0] / 512;  // 4096

  float* ws = (float*)d_ws;
  float* xln = ws;    ws += (size_t)T * 512;
  float* h = ws;      ws += (size_t)T * 512;
  float* nvphi = ws;  ws += (size_t)2048 * 256;
  float* actb = ws;   ws += (size_t)T * 64;
  int* idx = (int*)ws;   ws += (size_t)T * 64;
  u16* scoresb = (u16*)ws; ws += (size_t)T * 2048 / 2;
  u16* hb = (u16*)ws;    ws += (size_t)T * 512 / 2;
  u16* Wr2b = (u16*)ws;  ws += (size_t)2048 * 512 / 2;
  u16* pW2T = (u16*)ws;  ws += (size_t)2048 * 256 / 2;
  u16* rh = (u16*)ws;    ws += (size_t)T * 256 / 2;
  u16* t1b = (u16*)ws;   ws += (size_t)T * 512 / 2;
  u16* rW1T = (u16*)ws;  ws += (size_t)512 * 256 / 2;
  u16* rW2T = (u16*)ws;  ws += (size_t)512 * 512 / 2;

  k_prep<<<7424 + T, 256, 0, stream>>>(nv, pW1, pb1, nvphi, pW2, pW2T, rW1,
                                       rW1T, rW2, rW2T, Wr2, Wr2b, x, rn_g,
                                       rn_b, xln);
  gemm8f<2, true><<<dim3(512 / 128, T / 128), 256, 0, stream>>>(
      xln, Wr1, h, hb, T, 512, 512);
  gemm_mf<0, false, 1><<<dim3(2048 / 128, T / 64), 256, 0, stream>>>(
      hb, Wr2b, nullptr, scoresb, T, 2048, 512);
  k_topk_act<<<T, 256, 0, stream>>>(scoresb, h, Wr2, x, W_in, idx, actb);
  k_phi<<<T, 256, 0, stream>>>(nvphi, pW1, pln1_g, pln1_b, pW2T, pb2, pln2_g,
                               pln2_b, idx, actb, rln_g, rln_b, rh);
  gemm_mf<1, true, 1><<<dim3(512 / 128, T / 64), 256, 0, stream>>>(
      rh, rW1T, rb1, t1b, T, 512, 256);
  gemm_mf<0, true, 0><<<dim3(512 / 128, T / 64), 256, 0, stream>>>(
      t1b, rW2T, rb2, out, T, 512, 512);
}